// Round 1
// baseline (4449.326 us; speedup 1.0000x reference)
//
#include <hip/hip_runtime.h>

#define NN 100000
#define NE 800000

// ws layout (bytes):
//   cnt/inv : [0, 400000)                      N floats
//   agg     : [524288, +N*256*4)               reused: layer1 uses N*128, layer2 N*256
//   h       : [102924288, +N*256*4)
// total ~206 MB

__global__ void degree_k(const int* __restrict__ dst, float* __restrict__ cnt) {
  int e = blockIdx.x * 256 + threadIdx.x;
  if (e < NE) atomicAdd(&cnt[dst[e]], 1.0f);
}

__global__ void inv_k(float* cnt) {
  int i = blockIdx.x * 256 + threadIdx.x;
  if (i < NN) cnt[i] = 1.0f / fmaxf(cnt[i], 1.0f);
}

template<int D>
__global__ __launch_bounds__(256) void scatter_k(const float* __restrict__ feat,
    const int* __restrict__ src, const int* __restrict__ dst,
    float* __restrict__ agg) {
  constexpr int PER = D / 4;  // threads per edge
  int tid = blockIdx.x * 256 + threadIdx.x;
  int e = tid / PER;
  int f = (tid % PER) * 4;
  if (e >= NE) return;
  int s = src[e], d = dst[e];
  float4 v = *reinterpret_cast<const float4*>(feat + (size_t)s * D + f);
  float* p = agg + (size_t)d * D + f;
  atomicAdd(p + 0, v.x);
  atomicAdd(p + 1, v.y);
  atomicAdd(p + 2, v.z);
  atomicAdd(p + 3, v.w);
}

// C[M,NOUT] = act( (A1*inv) @ B1^T + A2 @ B2^T + bias )
// A row-major [M,K]; B row-major [NOUT,K]; BM=128 BN=64 BK=16, 256 thr, 8x4/thread
template<int K, int NOUT, bool RELU>
__global__ __launch_bounds__(256) void gemm_dual_k(
    const float* __restrict__ A1, const float* __restrict__ inv,
    const float* __restrict__ A2,
    const float* __restrict__ B1, const float* __restrict__ B2,
    const float* __restrict__ bias, float* __restrict__ out) {
  __shared__ float As[16][132];  // k-major, padded (2-way max on store, bcast on read)
  __shared__ float Bs[16][68];
  const int t = threadIdx.x;
  const int ty = t >> 4, tx = t & 15;
  const int row0 = blockIdx.x * 128, col0 = blockIdx.y * 64;

  float acc[8][4];
#pragma unroll
  for (int i = 0; i < 8; ++i)
#pragma unroll
    for (int j = 0; j < 4; ++j) acc[i][j] = 0.f;

#pragma unroll 1
  for (int pair = 0; pair < 2; ++pair) {
    const float* A = pair ? A2 : A1;
    const float* B = pair ? B2 : B1;
#pragma unroll 1
    for (int kt = 0; kt < K / 16; ++kt) {
      // A tile: 128 rows x 16 k  (512 float4, 2 per thread)
#pragma unroll
      for (int l = 0; l < 2; ++l) {
        int idx = t + l * 256;
        int r = idx >> 2, kq = idx & 3;
        int gr = row0 + r;
        float4 v = make_float4(0.f, 0.f, 0.f, 0.f);
        float sc = 1.f;
        if (gr < NN) {
          v = *reinterpret_cast<const float4*>(A + (size_t)gr * K + kt * 16 + kq * 4);
          if (pair == 0) sc = inv[gr];
        }
        As[kq * 4 + 0][r] = v.x * sc;
        As[kq * 4 + 1][r] = v.y * sc;
        As[kq * 4 + 2][r] = v.z * sc;
        As[kq * 4 + 3][r] = v.w * sc;
      }
      {  // B tile: 64 rows x 16 k (256 float4, 1 per thread)
        int r = t >> 2, kq = t & 3;
        float4 v = *reinterpret_cast<const float4*>(B + (size_t)(col0 + r) * K + kt * 16 + kq * 4);
        Bs[kq * 4 + 0][r] = v.x;
        Bs[kq * 4 + 1][r] = v.y;
        Bs[kq * 4 + 2][r] = v.z;
        Bs[kq * 4 + 3][r] = v.w;
      }
      __syncthreads();
#pragma unroll
      for (int kk = 0; kk < 16; ++kk) {
        float a[8], b[4];
#pragma unroll
        for (int i = 0; i < 8; ++i) a[i] = As[kk][ty * 8 + i];
#pragma unroll
        for (int j = 0; j < 4; ++j) b[j] = Bs[kk][tx * 4 + j];
#pragma unroll
        for (int i = 0; i < 8; ++i)
#pragma unroll
          for (int j = 0; j < 4; ++j) acc[i][j] = fmaf(a[i], b[j], acc[i][j]);
      }
      __syncthreads();
    }
  }

  float4 bv = *reinterpret_cast<const float4*>(bias + col0 + tx * 4);
#pragma unroll
  for (int i = 0; i < 8; ++i) {
    int gr = row0 + ty * 8 + i;
    if (gr < NN) {
      float4 c;
      c.x = acc[i][0] + bv.x;
      c.y = acc[i][1] + bv.y;
      c.z = acc[i][2] + bv.z;
      c.w = acc[i][3] + bv.w;
      if (RELU) {
        c.x = fmaxf(c.x, 0.f); c.y = fmaxf(c.y, 0.f);
        c.z = fmaxf(c.z, 0.f); c.w = fmaxf(c.w, 0.f);
      }
      *reinterpret_cast<float4*>(out + (size_t)gr * NOUT + col0 + tx * 4) = c;
    }
  }
}

extern "C" void kernel_launch(void* const* d_in, const int* in_sizes, int n_in,
                              void* d_out, int out_size, void* d_ws, size_t ws_size,
                              hipStream_t stream) {
  const float* x   = (const float*)d_in[0];
  const int*   ei  = (const int*)d_in[1];
  const float* W1l = (const float*)d_in[2];
  const float* b1  = (const float*)d_in[3];
  const float* W1r = (const float*)d_in[4];
  const float* W2l = (const float*)d_in[5];
  const float* b2  = (const float*)d_in[6];
  const float* W2r = (const float*)d_in[7];
  float* out = (float*)d_out;

  char* ws = (char*)d_ws;
  float* cnt = (float*)ws;                    // becomes inv after inv_k
  float* agg = (float*)(ws + 524288);
  float* h   = (float*)(ws + 102924288);

  const int* src = ei;
  const int* dst = ei + NE;

  hipMemsetAsync(cnt, 0, NN * sizeof(float), stream);
  hipMemsetAsync(agg, 0, (size_t)NN * 128 * sizeof(float), stream);
  degree_k<<<(NE + 255) / 256, 256, 0, stream>>>(dst, cnt);
  inv_k<<<(NN + 255) / 256, 256, 0, stream>>>(cnt);
  scatter_k<128><<<NE * 32 / 256, 256, 0, stream>>>(x, src, dst, agg);

  dim3 g1((NN + 127) / 128, 256 / 64);
  gemm_dual_k<128, 256, true><<<g1, 256, 0, stream>>>(agg, cnt, x, W1l, W1r, b1, h);

  hipMemsetAsync(agg, 0, (size_t)NN * 256 * sizeof(float), stream);
  scatter_k<256><<<NE * 64 / 256, 256, 0, stream>>>(h, src, dst, agg);

  dim3 g2((NN + 127) / 128, 128 / 64);
  gemm_dual_k<256, 128, false><<<g2, 256, 0, stream>>>(agg, cnt, h, W2l, W2r, b2, out);
}

// Round 2
// 593.272 us; speedup vs baseline: 7.4996x; 7.4996x over previous
//
#include <hip/hip_runtime.h>

#define NN 100000
#define NE 800000

// ws layout (bytes):
//   0x000000 : inv    (NN float)
//   0x080000 : deg    (NN int)
//   0x100000 : offs   (NN int)
//   0x180000 : cursor (NN int)
//   0x200000 : bsum   (256 int)
//   0x400000 : eidx   (NE int, 3.2MB)
//   0x800000 : m1/hW  (NN*128 float, 51.2MB)
//   0x3C00000: h      (NN*256 float, 102.4MB)   total ~163MB

__global__ void degree_k(const int* __restrict__ dst, int* __restrict__ deg) {
  int e = blockIdx.x * 256 + threadIdx.x;
  if (e < NE) atomicAdd(&deg[dst[e]], 1);
}

__global__ void inv_k(const int* __restrict__ deg, float* __restrict__ inv) {
  int i = blockIdx.x * 256 + threadIdx.x;
  if (i < NN) inv[i] = 1.0f / fmaxf((float)deg[i], 1.0f);
}

// block-level exclusive scan over 1024-chunks (256 thr x 4 elems)
__global__ __launch_bounds__(256) void scan1_k(const int* __restrict__ deg,
    int* __restrict__ offs, int* __restrict__ bsum) {
  __shared__ int s[256];
  int t = threadIdx.x;
  int base = blockIdx.x * 1024 + t * 4;
  int v[4], tsum = 0;
#pragma unroll
  for (int k = 0; k < 4; ++k) { int i = base + k; v[k] = (i < NN) ? deg[i] : 0; tsum += v[k]; }
  s[t] = tsum; __syncthreads();
  int val = tsum;
#pragma unroll
  for (int off = 1; off < 256; off <<= 1) {
    int x = (t >= off) ? s[t - off] : 0;
    __syncthreads();
    val += x; s[t] = val;
    __syncthreads();
  }
  int excl = val - tsum;
  if (t == 255) bsum[blockIdx.x] = val;
  int run = excl;
#pragma unroll
  for (int k = 0; k < 4; ++k) { int i = base + k; if (i < NN) offs[i] = run; run += v[k]; }
}

__global__ __launch_bounds__(256) void scan2_k(int* __restrict__ bsum, int nb) {
  __shared__ int s[256];
  int t = threadIdx.x;
  int v = (t < nb) ? bsum[t] : 0;
  s[t] = v; __syncthreads();
  int val = v;
#pragma unroll
  for (int off = 1; off < 256; off <<= 1) {
    int x = (t >= off) ? s[t - off] : 0;
    __syncthreads();
    val += x; s[t] = val;
    __syncthreads();
  }
  if (t < nb) bsum[t] = val - v;
}

__global__ __launch_bounds__(256) void scan3_k(int* __restrict__ offs,
    const int* __restrict__ bsum, int* __restrict__ cursor) {
  int base = blockIdx.x * 1024 + threadIdx.x * 4;
  int add = bsum[blockIdx.x];
#pragma unroll
  for (int k = 0; k < 4; ++k) {
    int i = base + k;
    if (i < NN) { int o = offs[i] + add; offs[i] = o; cursor[i] = o; }
  }
}

__global__ void fill_k(const int* __restrict__ src, const int* __restrict__ dst,
    int* __restrict__ cursor, int* __restrict__ eidx) {
  int e = blockIdx.x * 256 + threadIdx.x;
  if (e < NE) {
    int p = atomicAdd(&cursor[dst[e]], 1);
    eidx[p] = src[e];
  }
}

// per-node gather-reduce: G=D/4 lanes/node, float4/lane
// ACC=false: outp[node] = inv*sum ; ACC=true: outp[node] += inv*sum
template<int D, bool ACC>
__global__ __launch_bounds__(256) void gather_k(const float* __restrict__ feat,
    const int* __restrict__ offs, const int* __restrict__ deg,
    const float* __restrict__ inv, const int* __restrict__ eidx,
    float* __restrict__ outp) {
  constexpr int G = D / 4;
  constexpr int NPB = 256 / G;
  int node = blockIdx.x * NPB + threadIdx.x / G;
  int l = threadIdx.x % G;
  if (node >= NN) return;
  int st = offs[node], n = deg[node];
  float4 acc = make_float4(0.f, 0.f, 0.f, 0.f);
  for (int j = 0; j < n; ++j) {
    int s = eidx[st + j];
    float4 v = *reinterpret_cast<const float4*>(feat + (size_t)s * D + l * 4);
    acc.x += v.x; acc.y += v.y; acc.z += v.z; acc.w += v.w;
  }
  float sc = inv[node];
  float* po = outp + (size_t)node * D + l * 4;
  if (ACC) {
    float4 o = *reinterpret_cast<const float4*>(po);
    o.x += sc * acc.x; o.y += sc * acc.y; o.z += sc * acc.z; o.w += sc * acc.w;
    *reinterpret_cast<float4*>(po) = o;
  } else {
    float4 o = make_float4(sc * acc.x, sc * acc.y, sc * acc.z, sc * acc.w);
    *reinterpret_cast<float4*>(po) = o;
  }
}

// C[M,NOUT] = act( A1 @ B1^T [+ A2 @ B2^T] [+ bias] )
// A row-major [M,K]; B row-major [NOUT,K]; BM=128 BN=64 BK=16, 256 thr, 8x4/thread
template<int K, int NOUT, bool DUAL, bool BIAS, bool RELU>
__global__ __launch_bounds__(256) void gemm_k(
    const float* __restrict__ A1, const float* __restrict__ A2,
    const float* __restrict__ B1, const float* __restrict__ B2,
    const float* __restrict__ bias, float* __restrict__ out) {
  __shared__ float As[16][132];
  __shared__ float Bs[16][68];
  const int t = threadIdx.x;
  const int ty = t >> 4, tx = t & 15;
  const int row0 = blockIdx.x * 128, col0 = blockIdx.y * 64;

  float acc[8][4];
#pragma unroll
  for (int i = 0; i < 8; ++i)
#pragma unroll
    for (int j = 0; j < 4; ++j) acc[i][j] = 0.f;

  constexpr int NPAIR = DUAL ? 2 : 1;
#pragma unroll 1
  for (int pair = 0; pair < NPAIR; ++pair) {
    const float* A = (DUAL && pair) ? A2 : A1;
    const float* B = (DUAL && pair) ? B2 : B1;
#pragma unroll 1
    for (int kt = 0; kt < K / 16; ++kt) {
#pragma unroll
      for (int l = 0; l < 2; ++l) {
        int idx = t + l * 256;
        int r = idx >> 2, kq = idx & 3;
        int gr = row0 + r;
        float4 v = make_float4(0.f, 0.f, 0.f, 0.f);
        if (gr < NN) v = *reinterpret_cast<const float4*>(A + (size_t)gr * K + kt * 16 + kq * 4);
        As[kq * 4 + 0][r] = v.x;
        As[kq * 4 + 1][r] = v.y;
        As[kq * 4 + 2][r] = v.z;
        As[kq * 4 + 3][r] = v.w;
      }
      {
        int r = t >> 2, kq = t & 3;
        float4 v = *reinterpret_cast<const float4*>(B + (size_t)(col0 + r) * K + kt * 16 + kq * 4);
        Bs[kq * 4 + 0][r] = v.x;
        Bs[kq * 4 + 1][r] = v.y;
        Bs[kq * 4 + 2][r] = v.z;
        Bs[kq * 4 + 3][r] = v.w;
      }
      __syncthreads();
#pragma unroll
      for (int kk = 0; kk < 16; ++kk) {
        float a[8], b[4];
#pragma unroll
        for (int i = 0; i < 8; ++i) a[i] = As[kk][ty * 8 + i];
#pragma unroll
        for (int j = 0; j < 4; ++j) b[j] = Bs[kk][tx * 4 + j];
#pragma unroll
        for (int i = 0; i < 8; ++i)
#pragma unroll
          for (int j = 0; j < 4; ++j) acc[i][j] = fmaf(a[i], b[j], acc[i][j]);
      }
      __syncthreads();
    }
  }

  float4 bv = make_float4(0.f, 0.f, 0.f, 0.f);
  if (BIAS) bv = *reinterpret_cast<const float4*>(bias + col0 + tx * 4);
#pragma unroll
  for (int i = 0; i < 8; ++i) {
    int gr = row0 + ty * 8 + i;
    if (gr < NN) {
      float4 c;
      c.x = acc[i][0] + bv.x;
      c.y = acc[i][1] + bv.y;
      c.z = acc[i][2] + bv.z;
      c.w = acc[i][3] + bv.w;
      if (RELU) {
        c.x = fmaxf(c.x, 0.f); c.y = fmaxf(c.y, 0.f);
        c.z = fmaxf(c.z, 0.f); c.w = fmaxf(c.w, 0.f);
      }
      *reinterpret_cast<float4*>(out + (size_t)gr * NOUT + col0 + tx * 4) = c;
    }
  }
}

extern "C" void kernel_launch(void* const* d_in, const int* in_sizes, int n_in,
                              void* d_out, int out_size, void* d_ws, size_t ws_size,
                              hipStream_t stream) {
  const float* x   = (const float*)d_in[0];
  const int*   ei  = (const int*)d_in[1];
  const float* W1l = (const float*)d_in[2];
  const float* b1  = (const float*)d_in[3];
  const float* W1r = (const float*)d_in[4];
  const float* W2l = (const float*)d_in[5];
  const float* b2  = (const float*)d_in[6];
  const float* W2r = (const float*)d_in[7];
  float* out = (float*)d_out;

  char* ws = (char*)d_ws;
  float* inv    = (float*)(ws);
  int*   deg    = (int*)(ws + 0x80000);
  int*   offs   = (int*)(ws + 0x100000);
  int*   cursor = (int*)(ws + 0x180000);
  int*   bsum   = (int*)(ws + 0x200000);
  int*   eidx   = (int*)(ws + 0x400000);
  float* m1     = (float*)(ws + 0x800000);    // reused as hW in layer 2
  float* h      = (float*)(ws + 0x3C00000);

  const int* src = ei;
  const int* dst = ei + NE;

  const int NB = (NN + 1023) / 1024;  // 98

  // ---- CSR build ----
  hipMemsetAsync(deg, 0, NN * sizeof(int), stream);
  degree_k<<<(NE + 255) / 256, 256, 0, stream>>>(dst, deg);
  inv_k<<<(NN + 255) / 256, 256, 0, stream>>>(deg, inv);
  scan1_k<<<NB, 256, 0, stream>>>(deg, offs, bsum);
  scan2_k<<<1, 256, 0, stream>>>(bsum, NB);
  scan3_k<<<NB, 256, 0, stream>>>(offs, bsum, cursor);
  fill_k<<<(NE + 255) / 256, 256, 0, stream>>>(src, dst, cursor, eidx);

  // ---- layer 1: m1 = mean-agg(x); h = relu(m1@W1l.T + x@W1r.T + b1) ----
  gather_k<128, false><<<(NN + 7) / 8, 256, 0, stream>>>(x, offs, deg, inv, eidx, m1);
  dim3 g1((NN + 127) / 128, 256 / 64);
  gemm_k<128, 256, true, true, true><<<g1, 256, 0, stream>>>(m1, x, W1l, W1r, b1, h);

  // ---- layer 2 (transform-first): hW = h@W2l.T; out = h@W2r.T + b2; out += inv*gather(hW) ----
  float* hW = m1;
  dim3 g2((NN + 127) / 128, 128 / 64);
  gemm_k<256, 128, false, false, false><<<g2, 256, 0, stream>>>(h, nullptr, W2l, nullptr, nullptr, hW);
  gemm_k<256, 128, false, true, false><<<g2, 256, 0, stream>>>(h, nullptr, W2r, nullptr, b2, out);
  gather_k<128, true><<<(NN + 7) / 8, 256, 0, stream>>>(hW, offs, deg, inv, eidx, out);
}

// Round 3
// 383.876 us; speedup vs baseline: 11.5905x; 1.5455x over previous
//
#include <hip/hip_runtime.h>

#define NN 100000
#define NE 800000

typedef __attribute__((ext_vector_type(4))) float f32x4;
typedef __attribute__((ext_vector_type(4))) int   i32x4;

__device__ __forceinline__ unsigned short f2bf(float f) {
  unsigned u = __float_as_uint(f);
  return (unsigned short)((u + 0x7FFFu + ((u >> 16) & 1u)) >> 16);
}
__device__ __forceinline__ float bf2f(unsigned short b) {
  return __uint_as_float(((unsigned)b) << 16);
}

// ---------------- CSR build ----------------
__global__ void degree_k(const int* __restrict__ dst, int* __restrict__ deg) {
  int e = blockIdx.x * 256 + threadIdx.x;
  if (e < NE) atomicAdd(&deg[dst[e]], 1);
}

__global__ void inv_k(const int* __restrict__ deg, float* __restrict__ inv) {
  int i = blockIdx.x * 256 + threadIdx.x;
  if (i < NN) inv[i] = 1.0f / fmaxf((float)deg[i], 1.0f);
}

__global__ __launch_bounds__(256) void scan1_k(const int* __restrict__ deg,
    int* __restrict__ offs, int* __restrict__ bsum) {
  __shared__ int s[256];
  int t = threadIdx.x;
  int base = blockIdx.x * 1024 + t * 4;
  int v[4], tsum = 0;
#pragma unroll
  for (int k = 0; k < 4; ++k) { int i = base + k; v[k] = (i < NN) ? deg[i] : 0; tsum += v[k]; }
  s[t] = tsum; __syncthreads();
  int val = tsum;
#pragma unroll
  for (int off = 1; off < 256; off <<= 1) {
    int x = (t >= off) ? s[t - off] : 0;
    __syncthreads();
    val += x; s[t] = val;
    __syncthreads();
  }
  int excl = val - tsum;
  if (t == 255) bsum[blockIdx.x] = val;
  int run = excl;
#pragma unroll
  for (int k = 0; k < 4; ++k) { int i = base + k; if (i < NN) offs[i] = run; run += v[k]; }
}

__global__ __launch_bounds__(256) void scan2_k(int* __restrict__ bsum, int nb) {
  __shared__ int s[256];
  int t = threadIdx.x;
  int v = (t < nb) ? bsum[t] : 0;
  s[t] = v; __syncthreads();
  int val = v;
#pragma unroll
  for (int off = 1; off < 256; off <<= 1) {
    int x = (t >= off) ? s[t - off] : 0;
    __syncthreads();
    val += x; s[t] = val;
    __syncthreads();
  }
  if (t < nb) bsum[t] = val - v;
}

__global__ __launch_bounds__(256) void scan3_k(int* __restrict__ offs,
    const int* __restrict__ bsum, int* __restrict__ cursor) {
  int base = blockIdx.x * 1024 + threadIdx.x * 4;
  int add = bsum[blockIdx.x];
#pragma unroll
  for (int k = 0; k < 4; ++k) {
    int i = base + k;
    if (i < NN) { int o = offs[i] + add; offs[i] = o; cursor[i] = o; }
  }
}

__global__ void fill_k(const int* __restrict__ src, const int* __restrict__ dst,
    int* __restrict__ cursor, int* __restrict__ eidx) {
  int e = blockIdx.x * 256 + threadIdx.x;
  if (e < NE) {
    int p = atomicAdd(&cursor[dst[e]], 1);
    eidx[p] = src[e];
  }
}

// ---------------- casts ----------------
__global__ __launch_bounds__(256) void cast_x_k(const float* __restrict__ in,
    unsigned short* __restrict__ outb) {
  int i = blockIdx.x * 256 + threadIdx.x;       // one float4 per thread
  if (i >= NN * 128 / 4) return;
  float4 v = *reinterpret_cast<const float4*>(in + (size_t)i * 4);
  ushort4 o;
  o.x = f2bf(v.x); o.y = f2bf(v.y); o.z = f2bf(v.z); o.w = f2bf(v.w);
  *reinterpret_cast<ushort4*>(outb + (size_t)i * 4) = o;
}

// all four weight mats are 32768 elems each
__global__ __launch_bounds__(256) void cast_w4_k(const float* __restrict__ Wa,
    const float* __restrict__ Wb, const float* __restrict__ Wc,
    const float* __restrict__ Wd, unsigned short* __restrict__ outb) {
  int i = blockIdx.x * 256 + threadIdx.x;
  if (i >= 4 * 32768) return;
  int seg = i >> 15, off = i & 32767;
  const float* s = (seg < 2) ? (seg == 0 ? Wa : Wb) : (seg == 2 ? Wc : Wd);
  outb[i] = f2bf(s[off]);
}

// ---------------- gather (bf16 features, fp32 accum) ----------------
// D=128 bf16; G=32 lanes/node, 4 elems/lane.
// ACC=false: outp(bf16)[node] = bf16(inv*sum) ; ACC=true: outf(f32)[node] += inv*sum
template<bool ACC>
__global__ __launch_bounds__(256) void gather_k(const unsigned short* __restrict__ feat,
    const int* __restrict__ offs, const int* __restrict__ deg,
    const float* __restrict__ inv, const int* __restrict__ eidx,
    unsigned short* __restrict__ outb, float* __restrict__ outf) {
  int node = blockIdx.x * 8 + (threadIdx.x >> 5);
  int l = threadIdx.x & 31;
  if (node >= NN) return;
  int st = offs[node], n = deg[node];
  float a0 = 0.f, a1 = 0.f, a2 = 0.f, a3 = 0.f;
  for (int j = 0; j < n; ++j) {
    int s = eidx[st + j];
    ushort4 v = *reinterpret_cast<const ushort4*>(feat + (size_t)s * 128 + l * 4);
    a0 += bf2f(v.x); a1 += bf2f(v.y); a2 += bf2f(v.z); a3 += bf2f(v.w);
  }
  float sc = inv[node];
  if (ACC) {
    float* po = outf + (size_t)node * 128 + l * 4;
    float4 o = *reinterpret_cast<const float4*>(po);
    o.x += sc * a0; o.y += sc * a1; o.z += sc * a2; o.w += sc * a3;
    *reinterpret_cast<float4*>(po) = o;
  } else {
    ushort4 o;
    o.x = f2bf(sc * a0); o.y = f2bf(sc * a1); o.z = f2bf(sc * a2); o.w = f2bf(sc * a3);
    *reinterpret_cast<ushort4*>(outb + (size_t)node * 128 + l * 4) = o;
  }
}

// ---------------- bf16 MFMA GEMM ----------------
// C[M, ldc-chunk] = act( A @ B^T + bias ), A bf16 [M, 256] (DUAL: [M,128]|[M,128]),
// B bf16 row-major [NOUT, K]. Tile 128x64, 4 waves (2x2), full-K A panel in LDS
// with XOR-swizzle ((r&7)<<4) applied via pre-swizzled global source (T2+m173).
// OUT_MODE: 0 = bf16 store; 1 = f32 store + bias; 2 = bf16 store + bias + relu
template<bool DUAL, int OUT_MODE>
__global__ __launch_bounds__(256) void mgemm_k(
    const unsigned short* __restrict__ A1, const unsigned short* __restrict__ A2,
    const unsigned short* __restrict__ B1, const unsigned short* __restrict__ B2,
    const float* __restrict__ bias, void* __restrict__ outp, int ldc) {
  __shared__ unsigned short As[128 * 256];   // 64 KB, row stride 512 B
  const int t = threadIdx.x;
  const int wave = t >> 6, lane = t & 63;
  const int lhi = lane >> 4, llo = lane & 15;
  const int wm = wave >> 1, wn = wave & 1;
  const int row0 = blockIdx.x * 128;
  const int col0 = blockIdx.y * 64;

  // ---- stage A panel: 64 chunks of 1KB; swizzled source, linear LDS dest ----
#pragma unroll
  for (int c = 0; c < 16; ++c) {
    int chunk = wave * 16 + c;
    int tb = chunk * 1024 + lane * 16;   // byte within tile
    int r = tb >> 9;                     // 512 B per tile row
    int cb = tb & 511;
    int cbs = cb ^ ((r & 7) << 4);       // involutive XOR swizzle (bits 4-6)
    int gr = min(row0 + r, NN - 1);
    const char* gsrc;
    if (DUAL) {
      const unsigned short* Asel = (cbs < 256) ? A1 : A2;
      gsrc = (const char*)(Asel + (size_t)gr * 128) + (cbs & 255);
    } else {
      gsrc = (const char*)(A1 + (size_t)gr * 256) + cbs;
    }
    __builtin_amdgcn_global_load_lds(
        (const __attribute__((address_space(1))) void*)gsrc,
        (__attribute__((address_space(3))) void*)((char*)As + chunk * 1024),
        16, 0, 0);
  }

  // ---- preload all B fragments into registers (weights are L2-resident) ----
  i32x4 bfrag[8][2];
#pragma unroll
  for (int ks = 0; ks < 8; ++ks) {
#pragma unroll
    for (int fn = 0; fn < 2; ++fn) {
      int c = col0 + wn * 32 + fn * 16 + llo;
      const unsigned short* W;
      int k;
      if (DUAL) { W = (ks < 4) ? B1 : B2; k = (ks & 3) * 32 + lhi * 8; }
      else      { W = B1;                 k = ks * 32 + lhi * 8; }
      int ldb = DUAL ? 128 : 256;
      bfrag[ks][fn] = *reinterpret_cast<const i32x4*>(W + (size_t)c * ldb + k);
    }
  }

  __syncthreads();   // drains vmcnt (global_load_lds) + lgkmcnt

  // ---- K loop: 8 steps of 32, pure LDS->MFMA ----
  f32x4 acc[4][2];
#pragma unroll
  for (int fm = 0; fm < 4; ++fm)
#pragma unroll
    for (int fn = 0; fn < 2; ++fn) acc[fm][fn] = (f32x4)0.f;

#pragma unroll
  for (int ks = 0; ks < 8; ++ks) {
    i32x4 a[4];
#pragma unroll
    for (int fm = 0; fm < 4; ++fm) {
      int r = wm * 64 + fm * 16 + llo;
      int cb = (ks * 64 + lhi * 16) ^ ((r & 7) << 4);
      a[fm] = *reinterpret_cast<const i32x4*>((const char*)As + r * 512 + cb);
    }
#pragma unroll
    for (int fm = 0; fm < 4; ++fm)
#pragma unroll
      for (int fn = 0; fn < 2; ++fn)
        asm("v_mfma_f32_16x16x32_bf16 %0, %1, %2, %0"
            : "+v"(acc[fm][fn]) : "v"(a[fm]), "v"(bfrag[ks][fn]));
  }

  asm volatile("s_nop 7\n\ts_nop 7");   // MFMA -> VALU read hazard guard

  // ---- epilogue: C/D layout col=lane&15, row=(lane>>4)*4+reg ----
  float bv[2] = {0.f, 0.f};
  if (OUT_MODE >= 1) {
#pragma unroll
    for (int fn = 0; fn < 2; ++fn) bv[fn] = bias[col0 + wn * 32 + fn * 16 + llo];
  }
#pragma unroll
  for (int fm = 0; fm < 4; ++fm) {
#pragma unroll
    for (int fn = 0; fn < 2; ++fn) {
      int col = col0 + wn * 32 + fn * 16 + llo;
#pragma unroll
      for (int j = 0; j < 4; ++j) {
        int row = row0 + wm * 64 + fm * 16 + lhi * 4 + j;
        if (row < NN) {
          float v = acc[fm][fn][j] + bv[fn];
          if (OUT_MODE == 2) v = fmaxf(v, 0.f);
          if (OUT_MODE == 1)
            ((float*)outp)[(size_t)row * ldc + col] = v;
          else
            ((unsigned short*)outp)[(size_t)row * ldc + col] = f2bf(v);
        }
      }
    }
  }
}

extern "C" void kernel_launch(void* const* d_in, const int* in_sizes, int n_in,
                              void* d_out, int out_size, void* d_ws, size_t ws_size,
                              hipStream_t stream) {
  const float* x   = (const float*)d_in[0];
  const int*   ei  = (const int*)d_in[1];
  const float* W1l = (const float*)d_in[2];
  const float* b1  = (const float*)d_in[3];
  const float* W1r = (const float*)d_in[4];
  const float* W2l = (const float*)d_in[5];
  const float* b2  = (const float*)d_in[6];
  const float* W2r = (const float*)d_in[7];
  float* out = (float*)d_out;

  char* ws = (char*)d_ws;
  float*          inv    = (float*)(ws);
  int*            deg    = (int*)(ws + 0x80000);
  int*            offs   = (int*)(ws + 0x100000);
  int*            cursor = (int*)(ws + 0x180000);
  int*            bsum   = (int*)(ws + 0x200000);
  unsigned short* Wb     = (unsigned short*)(ws + 0x280000);  // 4 x 32768 bf16
  int*            eidx   = (int*)(ws + 0x400000);
  unsigned short* xb     = (unsigned short*)(ws + 0x800000);   // [NN,128] bf16
  unsigned short* m1b    = (unsigned short*)(ws + 0x2200000);  // [NN,128] bf16
  unsigned short* hb     = (unsigned short*)(ws + 0x3C00000);  // [NN,256] bf16
  unsigned short* hWb    = (unsigned short*)(ws + 0x6E00000);  // [NN,128] bf16

  unsigned short* W1lb = Wb;
  unsigned short* W1rb = Wb + 32768;
  unsigned short* W2lb = Wb + 65536;
  unsigned short* W2rb = Wb + 98304;

  const int* src = ei;
  const int* dst = ei + NE;
  const int NB = (NN + 1023) / 1024;  // 98

  // ---- CSR build ----
  hipMemsetAsync(deg, 0, NN * sizeof(int), stream);
  degree_k<<<(NE + 255) / 256, 256, 0, stream>>>(dst, deg);
  inv_k<<<(NN + 255) / 256, 256, 0, stream>>>(deg, inv);
  scan1_k<<<NB, 256, 0, stream>>>(deg, offs, bsum);
  scan2_k<<<1, 256, 0, stream>>>(bsum, NB);
  scan3_k<<<NB, 256, 0, stream>>>(offs, bsum, cursor);
  fill_k<<<(NE + 255) / 256, 256, 0, stream>>>(src, dst, cursor, eidx);

  // ---- casts ----
  cast_x_k<<<(NN * 128 / 4 + 255) / 256, 256, 0, stream>>>(x, xb);
  cast_w4_k<<<(4 * 32768 + 255) / 256, 256, 0, stream>>>(W1l, W1r, W2l, W2r, Wb);

  // ---- layer 1 ----
  gather_k<false><<<(NN + 7) / 8, 256, 0, stream>>>(xb, offs, deg, inv, eidx, m1b, nullptr);
  dim3 g1((NN + 127) / 128, 4);
  mgemm_k<true, 2><<<g1, 256, 0, stream>>>(m1b, xb, W1lb, W1rb, b1, hb, 256);

  // ---- layer 2 (transform-first) ----
  dim3 g2((NN + 127) / 128, 2);
  mgemm_k<false, 0><<<g2, 256, 0, stream>>>(hb, nullptr, W2lb, nullptr, nullptr, hWb, 128);
  mgemm_k<false, 1><<<g2, 256, 0, stream>>>(hb, nullptr, W2rb, nullptr, b2, out, 128);
  gather_k<true><<<(NN + 7) / 8, 256, 0, stream>>>(hWb, offs, deg, inv, eidx, nullptr, out);
}

// Round 4
// 321.507 us; speedup vs baseline: 13.8389x; 1.1940x over previous
//
#include <hip/hip_runtime.h>

#define NN 100000
#define NE 800000

typedef __attribute__((ext_vector_type(4))) float f32x4;
typedef __attribute__((ext_vector_type(4))) int   i32x4;

__device__ __forceinline__ unsigned short f2bf(float f) {
  unsigned u = __float_as_uint(f);
  return (unsigned short)((u + 0x7FFFu + ((u >> 16) & 1u)) >> 16);
}
__device__ __forceinline__ float bf2f(unsigned short b) {
  return __uint_as_float(((unsigned)b) << 16);
}

// ---------------- CSR build ----------------
__global__ void degree_k(const int* __restrict__ dst, int* __restrict__ deg) {
  int e = blockIdx.x * 256 + threadIdx.x;
  if (e < NE) atomicAdd(&deg[dst[e]], 1);
}

__global__ void inv_k(const int* __restrict__ deg, float* __restrict__ inv) {
  int i = blockIdx.x * 256 + threadIdx.x;
  if (i < NN) inv[i] = 1.0f / fmaxf((float)deg[i], 1.0f);
}

__global__ __launch_bounds__(256) void scan1_k(const int* __restrict__ deg,
    int* __restrict__ offs, int* __restrict__ bsum) {
  __shared__ int s[256];
  int t = threadIdx.x;
  int base = blockIdx.x * 1024 + t * 4;
  int v[4], tsum = 0;
#pragma unroll
  for (int k = 0; k < 4; ++k) { int i = base + k; v[k] = (i < NN) ? deg[i] : 0; tsum += v[k]; }
  s[t] = tsum; __syncthreads();
  int val = tsum;
#pragma unroll
  for (int off = 1; off < 256; off <<= 1) {
    int x = (t >= off) ? s[t - off] : 0;
    __syncthreads();
    val += x; s[t] = val;
    __syncthreads();
  }
  int excl = val - tsum;
  if (t == 255) bsum[blockIdx.x] = val;
  int run = excl;
#pragma unroll
  for (int k = 0; k < 4; ++k) { int i = base + k; if (i < NN) offs[i] = run; run += v[k]; }
}

__global__ __launch_bounds__(256) void scan2_k(int* __restrict__ bsum, int nb) {
  __shared__ int s[256];
  int t = threadIdx.x;
  int v = (t < nb) ? bsum[t] : 0;
  s[t] = v; __syncthreads();
  int val = v;
#pragma unroll
  for (int off = 1; off < 256; off <<= 1) {
    int x = (t >= off) ? s[t - off] : 0;
    __syncthreads();
    val += x; s[t] = val;
    __syncthreads();
  }
  if (t < nb) bsum[t] = val - v;
}

__global__ __launch_bounds__(256) void scan3_k(int* __restrict__ offs,
    const int* __restrict__ bsum, int* __restrict__ cursor) {
  int base = blockIdx.x * 1024 + threadIdx.x * 4;
  int add = bsum[blockIdx.x];
#pragma unroll
  for (int k = 0; k < 4; ++k) {
    int i = base + k;
    if (i < NN) { int o = offs[i] + add; offs[i] = o; cursor[i] = o; }
  }
}

__global__ void fill_k(const int* __restrict__ src, const int* __restrict__ dst,
    int* __restrict__ cursor, int* __restrict__ eidx) {
  int e = blockIdx.x * 256 + threadIdx.x;
  if (e < NE) {
    int p = atomicAdd(&cursor[dst[e]], 1);
    eidx[p] = src[e];
  }
}

// ---------------- casts ----------------
__global__ __launch_bounds__(256) void cast_x_k(const float* __restrict__ in,
    unsigned short* __restrict__ outb) {
  int i = blockIdx.x * 256 + threadIdx.x;       // one float4 per thread
  if (i >= NN * 128 / 4) return;
  float4 v = *reinterpret_cast<const float4*>(in + (size_t)i * 4);
  ushort4 o;
  o.x = f2bf(v.x); o.y = f2bf(v.y); o.z = f2bf(v.z); o.w = f2bf(v.w);
  *reinterpret_cast<ushort4*>(outb + (size_t)i * 4) = o;
}

// all four weight mats are 32768 elems each; packed contiguous into Wb
__global__ __launch_bounds__(256) void cast_w4_k(const float* __restrict__ Wa,
    const float* __restrict__ Wb, const float* __restrict__ Wc,
    const float* __restrict__ Wd, unsigned short* __restrict__ outb) {
  int i = blockIdx.x * 256 + threadIdx.x;
  if (i >= 4 * 32768) return;
  int seg = i >> 15, off = i & 32767;
  const float* s = (seg < 2) ? (seg == 0 ? Wa : Wb) : (seg == 2 ? Wc : Wd);
  outb[i] = f2bf(s[off]);
}

// ---------------- gather (bf16 features, fp32 accum) ----------------
template<bool ACC>
__global__ __launch_bounds__(256) void gather_k(const unsigned short* __restrict__ feat,
    const int* __restrict__ offs, const int* __restrict__ deg,
    const float* __restrict__ inv, const int* __restrict__ eidx,
    unsigned short* __restrict__ outb, float* __restrict__ outf) {
  int node = blockIdx.x * 8 + (threadIdx.x >> 5);
  int l = threadIdx.x & 31;
  if (node >= NN) return;
  int st = offs[node], n = deg[node];
  float a0 = 0.f, a1 = 0.f, a2 = 0.f, a3 = 0.f;
  for (int j = 0; j < n; ++j) {
    int s = eidx[st + j];
    ushort4 v = *reinterpret_cast<const ushort4*>(feat + (size_t)s * 128 + l * 4);
    a0 += bf2f(v.x); a1 += bf2f(v.y); a2 += bf2f(v.z); a3 += bf2f(v.w);
  }
  float sc = inv[node];
  if (ACC) {
    float* po = outf + (size_t)node * 128 + l * 4;
    float4 o = *reinterpret_cast<const float4*>(po);
    o.x += sc * a0; o.y += sc * a1; o.z += sc * a2; o.w += sc * a3;
    *reinterpret_cast<float4*>(po) = o;
  } else {
    ushort4 o;
    o.x = f2bf(sc * a0); o.y = f2bf(sc * a1); o.z = f2bf(sc * a2); o.w = f2bf(sc * a3);
    *reinterpret_cast<ushort4*>(outb + (size_t)node * 128 + l * 4) = o;
  }
}

// ---------------- bf16 MFMA GEMM, full-width (64 rows x 256 cols / block) --------
// Virtual C[M,256] = A[M,256] @ B[256,256]^T ; 4 waves, wave w owns cols [64w,64w+64).
// A panel staged to 32KB LDS via global_load_lds w/ pre-swizzled source (T2/m173);
// B fragments streamed from global per K-step (weights L2-resident).
// MODE 0 (layer 1): A = [A1|A2] k-concat (two [M,128] bf16), B k-concat
//   (Wbase: W1l at +0, W1r at +32768, each [256,128]); out = bf16 relu(C+bias) -> outb ldc 256.
// MODE 1 (layer 2): A = A1 [M,256]; B out-concat (Wbase: W2l at +0, W2r at +32768,
//   each [128,256]); cols 0-127 -> outb bf16 (no bias), cols 128-255 -> outf f32 + bias.
template<int MODE>
__global__ __launch_bounds__(256) void mgemm_k(
    const unsigned short* __restrict__ A1, const unsigned short* __restrict__ A2,
    const unsigned short* __restrict__ Wbase, const float* __restrict__ bias,
    unsigned short* __restrict__ outb, float* __restrict__ outf) {
  __shared__ unsigned short As[64 * 256];   // 32 KB, row stride 512 B
  const int t = threadIdx.x;
  const int wave = t >> 6, lane = t & 63;
  const int lhi = lane >> 4, llo = lane & 15;
  const int row0 = blockIdx.x * 64;

  // ---- stage A panel: 32 chunks of 1KB, 8 per wave; swizzled src, linear dest ----
#pragma unroll
  for (int c = 0; c < 8; ++c) {
    int chunk = wave * 8 + c;
    int tb = chunk * 1024 + lane * 16;   // byte within tile
    int r = tb >> 9;                     // 512 B per tile row
    int cb = tb & 511;
    int cbs = cb ^ ((r & 7) << 4);       // involutive XOR swizzle (bits 4-6)
    int gr = min(row0 + r, NN - 1);
    const char* gsrc;
    if (MODE == 0) {
      const unsigned short* Asel = (cbs < 256) ? A1 : A2;
      gsrc = (const char*)(Asel + (size_t)gr * 128) + (cbs & 255);
    } else {
      gsrc = (const char*)(A1 + (size_t)gr * 256) + cbs;
    }
    __builtin_amdgcn_global_load_lds(
        (const __attribute__((address_space(1))) void*)gsrc,
        (__attribute__((address_space(3))) void*)((char*)As + chunk * 1024),
        16, 0, 0);
  }

  // ---- per-wave B row-base pointers + bias ----
  const unsigned short* bp[4];
  float bv[4];
#pragma unroll
  for (int fn = 0; fn < 4; ++fn) {
    int c = wave * 64 + fn * 16 + llo;
    if (MODE == 0) {
      bp[fn] = Wbase + (size_t)c * 128;
      bv[fn] = bias[c];
    } else {
      bp[fn] = Wbase + (wave >= 2 ? 32768 : 0) + (size_t)(c & 127) * 256;
      bv[fn] = (wave >= 2) ? bias[c & 127] : 0.f;
    }
  }

  f32x4 acc[4][4];
#pragma unroll
  for (int fm = 0; fm < 4; ++fm)
#pragma unroll
    for (int fn = 0; fn < 4; ++fn) acc[fm][fn] = (f32x4)0.f;

  __syncthreads();   // drains vmcnt (global_load_lds)

  // ---- K loop: 8 steps of 32; unroll 1 keeps B-loads per-iter (VGPR control) ----
#pragma unroll 1
  for (int ks = 0; ks < 8; ++ks) {
    i32x4 a[4], b[4];
#pragma unroll
    for (int fm = 0; fm < 4; ++fm) {
      int r = fm * 16 + llo;
      int cb = (ks * 64 + lhi * 16) ^ ((r & 7) << 4);
      a[fm] = *reinterpret_cast<const i32x4*>((const char*)As + r * 512 + cb);
    }
    int koff = (MODE == 0) ? ((ks & 3) * 32 + lhi * 8 + ((ks >= 4) ? 32768 : 0))
                           : (ks * 32 + lhi * 8);
#pragma unroll
    for (int fn = 0; fn < 4; ++fn)
      b[fn] = *reinterpret_cast<const i32x4*>(bp[fn] + koff);
#pragma unroll
    for (int fm = 0; fm < 4; ++fm)
#pragma unroll
      for (int fn = 0; fn < 4; ++fn)
        asm("v_mfma_f32_16x16x32_bf16 %0, %1, %2, %0"
            : "+v"(acc[fm][fn]) : "v"(a[fm]), "v"(b[fn]));
  }

  asm volatile("s_nop 7\n\ts_nop 7");   // MFMA -> VALU read hazard guard

  // ---- epilogue: C/D layout col=lane&15, row=(lane>>4)*4+reg ----
#pragma unroll
  for (int fm = 0; fm < 4; ++fm) {
#pragma unroll
    for (int fn = 0; fn < 4; ++fn) {
      int col = wave * 64 + fn * 16 + llo;
#pragma unroll
      for (int j = 0; j < 4; ++j) {
        int row = row0 + fm * 16 + lhi * 4 + j;
        if (row < NN) {
          float v = acc[fm][fn][j] + bv[fn];
          if (MODE == 0) {
            v = fmaxf(v, 0.f);
            outb[(size_t)row * 256 + col] = f2bf(v);
          } else if (wave < 2) {
            outb[(size_t)row * 128 + col] = f2bf(v);
          } else {
            outf[(size_t)row * 128 + (col - 128)] = v;
          }
        }
      }
    }
  }
}

extern "C" void kernel_launch(void* const* d_in, const int* in_sizes, int n_in,
                              void* d_out, int out_size, void* d_ws, size_t ws_size,
                              hipStream_t stream) {
  const float* x   = (const float*)d_in[0];
  const int*   ei  = (const int*)d_in[1];
  const float* W1l = (const float*)d_in[2];
  const float* b1  = (const float*)d_in[3];
  const float* W1r = (const float*)d_in[4];
  const float* W2l = (const float*)d_in[5];
  const float* b2  = (const float*)d_in[6];
  const float* W2r = (const float*)d_in[7];
  float* out = (float*)d_out;

  char* ws = (char*)d_ws;
  float*          inv    = (float*)(ws);
  int*            deg    = (int*)(ws + 0x80000);
  int*            offs   = (int*)(ws + 0x100000);
  int*            cursor = (int*)(ws + 0x180000);
  int*            bsum   = (int*)(ws + 0x200000);
  unsigned short* Wb     = (unsigned short*)(ws + 0x280000);  // 4 x 32768 bf16, packed
  int*            eidx   = (int*)(ws + 0x400000);
  unsigned short* xb     = (unsigned short*)(ws + 0x800000);   // [NN,128] bf16
  unsigned short* m1b    = (unsigned short*)(ws + 0x2200000);  // [NN,128] bf16
  unsigned short* hb     = (unsigned short*)(ws + 0x3C00000);  // [NN,256] bf16
  unsigned short* hWb    = (unsigned short*)(ws + 0x6E00000);  // [NN,128] bf16

  const int* src = ei;
  const int* dst = ei + NE;
  const int NB = (NN + 1023) / 1024;  // 98

  // ---- CSR build ----
  hipMemsetAsync(deg, 0, NN * sizeof(int), stream);
  degree_k<<<(NE + 255) / 256, 256, 0, stream>>>(dst, deg);
  inv_k<<<(NN + 255) / 256, 256, 0, stream>>>(deg, inv);
  scan1_k<<<NB, 256, 0, stream>>>(deg, offs, bsum);
  scan2_k<<<1, 256, 0, stream>>>(bsum, NB);
  scan3_k<<<NB, 256, 0, stream>>>(offs, bsum, cursor);
  fill_k<<<(NE + 255) / 256, 256, 0, stream>>>(src, dst, cursor, eidx);

  // ---- casts ----
  cast_x_k<<<(NN * 128 / 4 + 255) / 256, 256, 0, stream>>>(x, xb);
  cast_w4_k<<<(4 * 32768 + 255) / 256, 256, 0, stream>>>(W1l, W1r, W2l, W2r, Wb);

  const int GB = (NN + 63) / 64;  // 1563

  // ---- layer 1: m1 = gather(x); h = relu([m1|x] @ [W1l|W1r]^T + b1) ----
  gather_k<false><<<(NN + 7) / 8, 256, 0, stream>>>(xb, offs, deg, inv, eidx, m1b, nullptr);
  mgemm_k<0><<<GB, 256, 0, stream>>>(m1b, xb, Wb, b1, hb, nullptr);

  // ---- layer 2 (transform-first, fused dual-output):
  //      hW = h@W2l.T (bf16), out = h@W2r.T + b2 (f32); then out += inv*gather(hW) ----
  mgemm_k<1><<<GB, 256, 0, stream>>>(hb, nullptr, Wb + 65536, b2, hWb, out);
  gather_k<true><<<(NN + 7) / 8, 256, 0, stream>>>(hWb, offs, deg, inv, eidx, nullptr, out);
}

// Round 5
// 278.833 us; speedup vs baseline: 15.9569x; 1.1530x over previous
//
#include <hip/hip_runtime.h>

#define NN 100000
#define NE 800000

typedef __attribute__((ext_vector_type(4))) float f32x4;
typedef __attribute__((ext_vector_type(4))) int   i32x4;
typedef __attribute__((ext_vector_type(8))) unsigned short u16x8;

__device__ __forceinline__ unsigned short f2bf(float f) {
  unsigned u = __float_as_uint(f);
  return (unsigned short)((u + 0x7FFFu + ((u >> 16) & 1u)) >> 16);
}
__device__ __forceinline__ float bf2f(unsigned short b) {
  return __uint_as_float(((unsigned)b) << 16);
}

// ---------------- CSR build ----------------
__global__ void degree_k(const int* __restrict__ dst, int* __restrict__ deg) {
  int e = blockIdx.x * 256 + threadIdx.x;
  if (e < NE) atomicAdd(&deg[dst[e]], 1);
}

__global__ void inv_k(const int* __restrict__ deg, float* __restrict__ inv) {
  int i = blockIdx.x * 256 + threadIdx.x;
  if (i < NN) inv[i] = 1.0f / fmaxf((float)deg[i], 1.0f);
}

__global__ __launch_bounds__(256) void scan1_k(const int* __restrict__ deg,
    int* __restrict__ offs, int* __restrict__ bsum) {
  __shared__ int s[256];
  int t = threadIdx.x;
  int base = blockIdx.x * 1024 + t * 4;
  int v[4], tsum = 0;
#pragma unroll
  for (int k = 0; k < 4; ++k) { int i = base + k; v[k] = (i < NN) ? deg[i] : 0; tsum += v[k]; }
  s[t] = tsum; __syncthreads();
  int val = tsum;
#pragma unroll
  for (int off = 1; off < 256; off <<= 1) {
    int x = (t >= off) ? s[t - off] : 0;
    __syncthreads();
    val += x; s[t] = val;
    __syncthreads();
  }
  int excl = val - tsum;
  if (t == 255) bsum[blockIdx.x] = val;
  int run = excl;
#pragma unroll
  for (int k = 0; k < 4; ++k) { int i = base + k; if (i < NN) offs[i] = run; run += v[k]; }
}

__global__ __launch_bounds__(256) void scan2_k(int* __restrict__ bsum, int nb) {
  __shared__ int s[256];
  int t = threadIdx.x;
  int v = (t < nb) ? bsum[t] : 0;
  s[t] = v; __syncthreads();
  int val = v;
#pragma unroll
  for (int off = 1; off < 256; off <<= 1) {
    int x = (t >= off) ? s[t - off] : 0;
    __syncthreads();
    val += x; s[t] = val;
    __syncthreads();
  }
  if (t < nb) bsum[t] = val - v;
}

__global__ __launch_bounds__(256) void scan3_k(int* __restrict__ offs,
    const int* __restrict__ bsum, int* __restrict__ cursor) {
  int base = blockIdx.x * 1024 + threadIdx.x * 4;
  int add = bsum[blockIdx.x];
#pragma unroll
  for (int k = 0; k < 4; ++k) {
    int i = base + k;
    if (i < NN) { int o = offs[i] + add; offs[i] = o; cursor[i] = o; }
  }
}

__global__ void fill_k(const int* __restrict__ src, const int* __restrict__ dst,
    int* __restrict__ cursor, int* __restrict__ eidx) {
  int e = blockIdx.x * 256 + threadIdx.x;
  if (e < NE) {
    int p = atomicAdd(&cursor[dst[e]], 1);
    eidx[p] = src[e];
  }
}

// ---------------- casts ----------------
__global__ __launch_bounds__(256) void cast_x_k(const float* __restrict__ in,
    unsigned short* __restrict__ outb) {
  int i = blockIdx.x * 256 + threadIdx.x;       // one float4 per thread
  if (i >= NN * 128 / 4) return;
  float4 v = *reinterpret_cast<const float4*>(in + (size_t)i * 4);
  ushort4 o;
  o.x = f2bf(v.x); o.y = f2bf(v.y); o.z = f2bf(v.z); o.w = f2bf(v.w);
  *reinterpret_cast<ushort4*>(outb + (size_t)i * 4) = o;
}

// all four weight mats are 32768 elems each; packed contiguous into Wb
__global__ __launch_bounds__(256) void cast_w4_k(const float* __restrict__ Wa,
    const float* __restrict__ Wb, const float* __restrict__ Wc,
    const float* __restrict__ Wd, unsigned short* __restrict__ outb) {
  int i = blockIdx.x * 256 + threadIdx.x;
  if (i >= 4 * 32768) return;
  int seg = i >> 15, off = i & 32767;
  const float* s = (seg < 2) ? (seg == 0 ? Wa : Wb) : (seg == 2 ? Wc : Wd);
  outb[i] = f2bf(s[off]);
}

// ---------------- gather (bf16 features, fp32 accum) ----------------
// 16 lanes/node, 16B (8 bf16) per lane; degree loop unrolled x4 so 4 row-loads
// are in flight per lane-group (prev version had VGPR=12 -> serial loads).
template<bool ACC>
__global__ __launch_bounds__(256) void gather_k(const unsigned short* __restrict__ feat,
    const int* __restrict__ offs, const int* __restrict__ deg,
    const float* __restrict__ inv, const int* __restrict__ eidx,
    unsigned short* __restrict__ outb, float* __restrict__ outf) {
  int node = blockIdx.x * 16 + (threadIdx.x >> 4);
  int l = threadIdx.x & 15;
  if (node >= NN) return;
  int st = offs[node], n = deg[node];
  float a[8];
#pragma unroll
  for (int k = 0; k < 8; ++k) a[k] = 0.f;

  int j = 0;
  for (; j + 4 <= n; j += 4) {
    int s0 = eidx[st + j + 0];
    int s1 = eidx[st + j + 1];
    int s2 = eidx[st + j + 2];
    int s3 = eidx[st + j + 3];
    u16x8 r0 = *reinterpret_cast<const u16x8*>(feat + (size_t)s0 * 128 + l * 8);
    u16x8 r1 = *reinterpret_cast<const u16x8*>(feat + (size_t)s1 * 128 + l * 8);
    u16x8 r2 = *reinterpret_cast<const u16x8*>(feat + (size_t)s2 * 128 + l * 8);
    u16x8 r3 = *reinterpret_cast<const u16x8*>(feat + (size_t)s3 * 128 + l * 8);
#pragma unroll
    for (int k = 0; k < 8; ++k)
      a[k] += (bf2f(r0[k]) + bf2f(r1[k])) + (bf2f(r2[k]) + bf2f(r3[k]));
  }
  for (; j < n; ++j) {
    int s = eidx[st + j];
    u16x8 r = *reinterpret_cast<const u16x8*>(feat + (size_t)s * 128 + l * 8);
#pragma unroll
    for (int k = 0; k < 8; ++k) a[k] += bf2f(r[k]);
  }

  float sc = inv[node];
  if (ACC) {
    float* po = outf + (size_t)node * 128 + l * 8;
    float4 o0 = *reinterpret_cast<const float4*>(po);
    float4 o1 = *reinterpret_cast<const float4*>(po + 4);
    o0.x += sc * a[0]; o0.y += sc * a[1]; o0.z += sc * a[2]; o0.w += sc * a[3];
    o1.x += sc * a[4]; o1.y += sc * a[5]; o1.z += sc * a[6]; o1.w += sc * a[7];
    *reinterpret_cast<float4*>(po) = o0;
    *reinterpret_cast<float4*>(po + 4) = o1;
  } else {
    u16x8 o;
#pragma unroll
    for (int k = 0; k < 8; ++k) o[k] = f2bf(sc * a[k]);
    *reinterpret_cast<u16x8*>(outb + (size_t)node * 128 + l * 8) = o;
  }
}

// ---------------- bf16 MFMA GEMM, full-width (64 rows x 256 cols / block) --------
// Virtual C[M,256] = A[M,256] @ B[256,256]^T ; 4 waves, wave w owns cols [64w,64w+64).
// A panel staged to 32KB LDS via global_load_lds w/ pre-swizzled source (T2/m173);
// B fragments streamed from global per K-step (weights L2-resident).
// MODE 0 (layer 1): A = [A1|A2] k-concat (two [M,128] bf16), B k-concat
//   (Wbase: W1l at +0, W1r at +32768, each [256,128]); out = bf16 relu(C+bias) -> outb ldc 256.
// MODE 1 (layer 2): A = A1 [M,256]; B out-concat (Wbase: W2l at +0, W2r at +32768,
//   each [128,256]); cols 0-127 -> outb bf16 (no bias), cols 128-255 -> outf f32 + bias.
template<int MODE>
__global__ __launch_bounds__(256) void mgemm_k(
    const unsigned short* __restrict__ A1, const unsigned short* __restrict__ A2,
    const unsigned short* __restrict__ Wbase, const float* __restrict__ bias,
    unsigned short* __restrict__ outb, float* __restrict__ outf) {
  __shared__ unsigned short As[64 * 256];   // 32 KB, row stride 512 B
  const int t = threadIdx.x;
  const int wave = t >> 6, lane = t & 63;
  const int lhi = lane >> 4, llo = lane & 15;
  const int row0 = blockIdx.x * 64;

  // ---- stage A panel: 32 chunks of 1KB, 8 per wave; swizzled src, linear dest ----
#pragma unroll
  for (int c = 0; c < 8; ++c) {
    int chunk = wave * 8 + c;
    int tb = chunk * 1024 + lane * 16;   // byte within tile
    int r = tb >> 9;                     // 512 B per tile row
    int cb = tb & 511;
    int cbs = cb ^ ((r & 7) << 4);       // involutive XOR swizzle (bits 4-6)
    int gr = min(row0 + r, NN - 1);
    const char* gsrc;
    if (MODE == 0) {
      const unsigned short* Asel = (cbs < 256) ? A1 : A2;
      gsrc = (const char*)(Asel + (size_t)gr * 128) + (cbs & 255);
    } else {
      gsrc = (const char*)(A1 + (size_t)gr * 256) + cbs;
    }
    __builtin_amdgcn_global_load_lds(
        (const __attribute__((address_space(1))) void*)gsrc,
        (__attribute__((address_space(3))) void*)((char*)As + chunk * 1024),
        16, 0, 0);
  }

  // ---- per-wave B row-base pointers + bias ----
  const unsigned short* bp[4];
  float bv[4];
#pragma unroll
  for (int fn = 0; fn < 4; ++fn) {
    int c = wave * 64 + fn * 16 + llo;
    if (MODE == 0) {
      bp[fn] = Wbase + (size_t)c * 128;
      bv[fn] = bias[c];
    } else {
      bp[fn] = Wbase + (wave >= 2 ? 32768 : 0) + (size_t)(c & 127) * 256;
      bv[fn] = (wave >= 2) ? bias[c & 127] : 0.f;
    }
  }

  f32x4 acc[4][4];
#pragma unroll
  for (int fm = 0; fm < 4; ++fm)
#pragma unroll
    for (int fn = 0; fn < 4; ++fn) acc[fm][fn] = (f32x4)0.f;

  __syncthreads();   // drains vmcnt (global_load_lds)

  // ---- K loop: 8 steps of 32; unroll 1 keeps B-loads per-iter (VGPR control) ----
#pragma unroll 1
  for (int ks = 0; ks < 8; ++ks) {
    i32x4 a[4], b[4];
#pragma unroll
    for (int fm = 0; fm < 4; ++fm) {
      int r = fm * 16 + llo;
      int cb = (ks * 64 + lhi * 16) ^ ((r & 7) << 4);
      a[fm] = *reinterpret_cast<const i32x4*>((const char*)As + r * 512 + cb);
    }
    int koff = (MODE == 0) ? ((ks & 3) * 32 + lhi * 8 + ((ks >= 4) ? 32768 : 0))
                           : (ks * 32 + lhi * 8);
#pragma unroll
    for (int fn = 0; fn < 4; ++fn)
      b[fn] = *reinterpret_cast<const i32x4*>(bp[fn] + koff);
#pragma unroll
    for (int fm = 0; fm < 4; ++fm)
#pragma unroll
      for (int fn = 0; fn < 4; ++fn)
        asm("v_mfma_f32_16x16x32_bf16 %0, %1, %2, %0"
            : "+v"(acc[fm][fn]) : "v"(a[fm]), "v"(b[fn]));
  }

  asm volatile("s_nop 7\n\ts_nop 7");   // MFMA -> VALU read hazard guard

  // ---- epilogue: C/D layout col=lane&15, row=(lane>>4)*4+reg ----
#pragma unroll
  for (int fm = 0; fm < 4; ++fm) {
#pragma unroll
    for (int fn = 0; fn < 4; ++fn) {
      int col = wave * 64 + fn * 16 + llo;
#pragma unroll
      for (int j = 0; j < 4; ++j) {
        int row = row0 + fm * 16 + lhi * 4 + j;
        if (row < NN) {
          float v = acc[fm][fn][j] + bv[fn];
          if (MODE == 0) {
            v = fmaxf(v, 0.f);
            outb[(size_t)row * 256 + col] = f2bf(v);
          } else if (wave < 2) {
            outb[(size_t)row * 128 + col] = f2bf(v);
          } else {
            outf[(size_t)row * 128 + (col - 128)] = v;
          }
        }
      }
    }
  }
}

extern "C" void kernel_launch(void* const* d_in, const int* in_sizes, int n_in,
                              void* d_out, int out_size, void* d_ws, size_t ws_size,
                              hipStream_t stream) {
  const float* x   = (const float*)d_in[0];
  const int*   ei  = (const int*)d_in[1];
  const float* W1l = (const float*)d_in[2];
  const float* b1  = (const float*)d_in[3];
  const float* W1r = (const float*)d_in[4];
  const float* W2l = (const float*)d_in[5];
  const float* b2  = (const float*)d_in[6];
  const float* W2r = (const float*)d_in[7];
  float* out = (float*)d_out;

  char* ws = (char*)d_ws;
  float*          inv    = (float*)(ws);
  int*            deg    = (int*)(ws + 0x80000);
  int*            offs   = (int*)(ws + 0x100000);
  int*            cursor = (int*)(ws + 0x180000);
  int*            bsum   = (int*)(ws + 0x200000);
  unsigned short* Wb     = (unsigned short*)(ws + 0x280000);  // 4 x 32768 bf16, packed
  int*            eidx   = (int*)(ws + 0x400000);
  unsigned short* xb     = (unsigned short*)(ws + 0x800000);   // [NN,128] bf16
  unsigned short* m1b    = (unsigned short*)(ws + 0x2200000);  // [NN,128] bf16
  unsigned short* hb     = (unsigned short*)(ws + 0x3C00000);  // [NN,256] bf16
  unsigned short* hWb    = (unsigned short*)(ws + 0x6E00000);  // [NN,128] bf16

  const int* src = ei;
  const int* dst = ei + NE;
  const int NB = (NN + 1023) / 1024;  // 98

  // ---- CSR build ----
  hipMemsetAsync(deg, 0, NN * sizeof(int), stream);
  degree_k<<<(NE + 255) / 256, 256, 0, stream>>>(dst, deg);
  inv_k<<<(NN + 255) / 256, 256, 0, stream>>>(deg, inv);
  scan1_k<<<NB, 256, 0, stream>>>(deg, offs, bsum);
  scan2_k<<<1, 256, 0, stream>>>(bsum, NB);
  scan3_k<<<NB, 256, 0, stream>>>(offs, bsum, cursor);
  fill_k<<<(NE + 255) / 256, 256, 0, stream>>>(src, dst, cursor, eidx);

  // ---- casts ----
  cast_x_k<<<(NN * 128 / 4 + 255) / 256, 256, 0, stream>>>(x, xb);
  cast_w4_k<<<(4 * 32768 + 255) / 256, 256, 0, stream>>>(W1l, W1r, W2l, W2r, Wb);

  const int GB = (NN + 63) / 64;  // 1563

  // ---- layer 1: m1 = gather(x); h = relu([m1|x] @ [W1l|W1r]^T + b1) ----
  gather_k<false><<<(NN + 15) / 16, 256, 0, stream>>>(xb, offs, deg, inv, eidx, m1b, nullptr);
  mgemm_k<0><<<GB, 256, 0, stream>>>(m1b, xb, Wb, b1, hb, nullptr);

  // ---- layer 2 (transform-first, fused dual-output):
  //      hW = h@W2l.T (bf16), out = h@W2r.T + b2 (f32); then out += inv*gather(hW) ----
  mgemm_k<1><<<GB, 256, 0, stream>>>(hb, nullptr, Wb + 65536, b2, hWb, out);
  gather_k<true><<<(NN + 15) / 16, 256, 0, stream>>>(hWb, offs, deg, inv, eidx, nullptr, out);
}

// Round 6
// 249.947 us; speedup vs baseline: 17.8011x; 1.1156x over previous
//
#include <hip/hip_runtime.h>

#define NN 100000
#define NE 800000

typedef __attribute__((ext_vector_type(4))) float f32x4;
typedef __attribute__((ext_vector_type(4))) int   i32x4;
typedef __attribute__((ext_vector_type(8))) unsigned short u16x8;

__device__ __forceinline__ unsigned short f2bf(float f) {
  unsigned u = __float_as_uint(f);
  return (unsigned short)((u + 0x7FFFu + ((u >> 16) & 1u)) >> 16);
}
__device__ __forceinline__ float bf2f(unsigned short b) {
  return __uint_as_float(((unsigned)b) << 16);
}

// ---------------- CSR build ----------------
// degree + per-edge within-node ordinal (atomicAdd return), so fill needs no atomics
__global__ void degree_k(const int* __restrict__ dst, int* __restrict__ deg,
                         int* __restrict__ rord) {
  int e = blockIdx.x * 256 + threadIdx.x;
  if (e < NE) rord[e] = atomicAdd(&deg[dst[e]], 1);
}

// block-level exclusive scan over 1024-chunks; also emits inv = 1/max(deg,1)
__global__ __launch_bounds__(256) void scan1_k(const int* __restrict__ deg,
    int* __restrict__ offs, int* __restrict__ bsum, float* __restrict__ inv) {
  __shared__ int s[256];
  int t = threadIdx.x;
  int base = blockIdx.x * 1024 + t * 4;
  int v[4], tsum = 0;
#pragma unroll
  for (int k = 0; k < 4; ++k) {
    int i = base + k;
    v[k] = (i < NN) ? deg[i] : 0;
    tsum += v[k];
    if (i < NN) inv[i] = 1.0f / fmaxf((float)v[k], 1.0f);
  }
  s[t] = tsum; __syncthreads();
  int val = tsum;
#pragma unroll
  for (int off = 1; off < 256; off <<= 1) {
    int x = (t >= off) ? s[t - off] : 0;
    __syncthreads();
    val += x; s[t] = val;
    __syncthreads();
  }
  int excl = val - tsum;
  if (t == 255) bsum[blockIdx.x] = val;
  int run = excl;
#pragma unroll
  for (int k = 0; k < 4; ++k) { int i = base + k; if (i < NN) offs[i] = run; run += v[k]; }
}

__global__ __launch_bounds__(256) void scan2_k(int* __restrict__ bsum, int nb) {
  __shared__ int s[256];
  int t = threadIdx.x;
  int v = (t < nb) ? bsum[t] : 0;
  s[t] = v; __syncthreads();
  int val = v;
#pragma unroll
  for (int off = 1; off < 256; off <<= 1) {
    int x = (t >= off) ? s[t - off] : 0;
    __syncthreads();
    val += x; s[t] = val;
    __syncthreads();
  }
  if (t < nb) bsum[t] = val - v;
}

__global__ __launch_bounds__(256) void scan3_k(int* __restrict__ offs,
    const int* __restrict__ bsum) {
  int base = blockIdx.x * 1024 + threadIdx.x * 4;
  int add = bsum[blockIdx.x];
#pragma unroll
  for (int k = 0; k < 4; ++k) {
    int i = base + k;
    if (i < NN) offs[i] += add;
  }
}

// atomic-free fill: p = offs[dst] + ordinal; nt store to reduce L2 line churn
__global__ void fill_k(const int* __restrict__ src, const int* __restrict__ dst,
    const int* __restrict__ offs, const int* __restrict__ rord,
    int* __restrict__ eidx) {
  int e = blockIdx.x * 256 + threadIdx.x;
  if (e < NE) {
    int p = offs[dst[e]] + rord[e];
    __builtin_nontemporal_store(src[e], &eidx[p]);
  }
}

// ---------------- casts ----------------
__global__ __launch_bounds__(256) void cast_x_k(const float* __restrict__ in,
    unsigned short* __restrict__ outb) {
  int i = blockIdx.x * 256 + threadIdx.x;       // one float4 per thread
  if (i >= NN * 128 / 4) return;
  float4 v = *reinterpret_cast<const float4*>(in + (size_t)i * 4);
  ushort4 o;
  o.x = f2bf(v.x); o.y = f2bf(v.y); o.z = f2bf(v.z); o.w = f2bf(v.w);
  *reinterpret_cast<ushort4*>(outb + (size_t)i * 4) = o;
}

// all four weight mats are 32768 elems each; packed contiguous into Wb
__global__ __launch_bounds__(256) void cast_w4_k(const float* __restrict__ Wa,
    const float* __restrict__ Wb, const float* __restrict__ Wc,
    const float* __restrict__ Wd, unsigned short* __restrict__ outb) {
  int i = blockIdx.x * 256 + threadIdx.x;
  if (i >= 4 * 32768) return;
  int seg = i >> 15, off = i & 32767;
  const float* s = (seg < 2) ? (seg == 0 ? Wa : Wb) : (seg == 2 ? Wc : Wd);
  outb[i] = f2bf(s[off]);
}

// ---------------- gather (bf16 features, fp32 accum) ----------------
// 16 lanes/node, 16B (8 bf16) per lane; degree loop unrolled x4 so 4 row-loads
// are in flight per lane-group.
template<bool ACC>
__global__ __launch_bounds__(256) void gather_k(const unsigned short* __restrict__ feat,
    const int* __restrict__ offs, const int* __restrict__ deg,
    const float* __restrict__ inv, const int* __restrict__ eidx,
    unsigned short* __restrict__ outb, float* __restrict__ outf) {
  int node = blockIdx.x * 16 + (threadIdx.x >> 4);
  int l = threadIdx.x & 15;
  if (node >= NN) return;
  int st = offs[node], n = deg[node];
  float a[8];
#pragma unroll
  for (int k = 0; k < 8; ++k) a[k] = 0.f;

  int j = 0;
  for (; j + 4 <= n; j += 4) {
    int s0 = eidx[st + j + 0];
    int s1 = eidx[st + j + 1];
    int s2 = eidx[st + j + 2];
    int s3 = eidx[st + j + 3];
    u16x8 r0 = *reinterpret_cast<const u16x8*>(feat + (size_t)s0 * 128 + l * 8);
    u16x8 r1 = *reinterpret_cast<const u16x8*>(feat + (size_t)s1 * 128 + l * 8);
    u16x8 r2 = *reinterpret_cast<const u16x8*>(feat + (size_t)s2 * 128 + l * 8);
    u16x8 r3 = *reinterpret_cast<const u16x8*>(feat + (size_t)s3 * 128 + l * 8);
#pragma unroll
    for (int k = 0; k < 8; ++k)
      a[k] += (bf2f(r0[k]) + bf2f(r1[k])) + (bf2f(r2[k]) + bf2f(r3[k]));
  }
  for (; j < n; ++j) {
    int s = eidx[st + j];
    u16x8 r = *reinterpret_cast<const u16x8*>(feat + (size_t)s * 128 + l * 8);
#pragma unroll
    for (int k = 0; k < 8; ++k) a[k] += bf2f(r[k]);
  }

  float sc = inv[node];
  if (ACC) {
    float* po = outf + (size_t)node * 128 + l * 8;
    float4 o0 = *reinterpret_cast<const float4*>(po);
    float4 o1 = *reinterpret_cast<const float4*>(po + 4);
    o0.x += sc * a[0]; o0.y += sc * a[1]; o0.z += sc * a[2]; o0.w += sc * a[3];
    o1.x += sc * a[4]; o1.y += sc * a[5]; o1.z += sc * a[6]; o1.w += sc * a[7];
    *reinterpret_cast<float4*>(po) = o0;
    *reinterpret_cast<float4*>(po + 4) = o1;
  } else {
    u16x8 o;
#pragma unroll
    for (int k = 0; k < 8; ++k) o[k] = f2bf(sc * a[k]);
    *reinterpret_cast<u16x8*>(outb + (size_t)node * 128 + l * 8) = o;
  }
}

// ---------------- bf16 MFMA GEMM, full-width (64 rows x 256 cols / block) --------
// Virtual C[M,256] = A[M,256] @ B[256,256]^T ; 4 waves, wave w owns cols [64w,64w+64).
// A panel staged to 32KB LDS via global_load_lds w/ pre-swizzled source (T2/m173);
// B fragments streamed from global per K-step (weights L2-resident).
// MODE 0 (layer 1): A = [A1|A2] k-concat (two [M,128] bf16), B k-concat
//   (Wbase: W1l at +0, W1r at +32768, each [256,128]); out = bf16 relu(C+bias) -> outb ldc 256.
// MODE 1 (layer 2): A = A1 [M,256]; B out-concat (Wbase: W2l at +0, W2r at +32768,
//   each [128,256]); cols 0-127 -> outb bf16 (no bias), cols 128-255 -> outf f32 + bias.
template<int MODE>
__global__ __launch_bounds__(256) void mgemm_k(
    const unsigned short* __restrict__ A1, const unsigned short* __restrict__ A2,
    const unsigned short* __restrict__ Wbase, const float* __restrict__ bias,
    unsigned short* __restrict__ outb, float* __restrict__ outf) {
  __shared__ unsigned short As[64 * 256];   // 32 KB, row stride 512 B
  const int t = threadIdx.x;
  const int wave = t >> 6, lane = t & 63;
  const int lhi = lane >> 4, llo = lane & 15;
  const int row0 = blockIdx.x * 64;

  // ---- stage A panel: 32 chunks of 1KB, 8 per wave; swizzled src, linear dest ----
#pragma unroll
  for (int c = 0; c < 8; ++c) {
    int chunk = wave * 8 + c;
    int tb = chunk * 1024 + lane * 16;   // byte within tile
    int r = tb >> 9;                     // 512 B per tile row
    int cb = tb & 511;
    int cbs = cb ^ ((r & 7) << 4);       // involutive XOR swizzle (bits 4-6)
    int gr = min(row0 + r, NN - 1);
    const char* gsrc;
    if (MODE == 0) {
      const unsigned short* Asel = (cbs < 256) ? A1 : A2;
      gsrc = (const char*)(Asel + (size_t)gr * 128) + (cbs & 255);
    } else {
      gsrc = (const char*)(A1 + (size_t)gr * 256) + cbs;
    }
    __builtin_amdgcn_global_load_lds(
        (const __attribute__((address_space(1))) void*)gsrc,
        (__attribute__((address_space(3))) void*)((char*)As + chunk * 1024),
        16, 0, 0);
  }

  // ---- per-wave B row-base pointers + bias ----
  const unsigned short* bp[4];
  float bv[4];
#pragma unroll
  for (int fn = 0; fn < 4; ++fn) {
    int c = wave * 64 + fn * 16 + llo;
    if (MODE == 0) {
      bp[fn] = Wbase + (size_t)c * 128;
      bv[fn] = bias[c];
    } else {
      bp[fn] = Wbase + (wave >= 2 ? 32768 : 0) + (size_t)(c & 127) * 256;
      bv[fn] = (wave >= 2) ? bias[c & 127] : 0.f;
    }
  }

  f32x4 acc[4][4];
#pragma unroll
  for (int fm = 0; fm < 4; ++fm)
#pragma unroll
    for (int fn = 0; fn < 4; ++fn) acc[fm][fn] = (f32x4)0.f;

  __syncthreads();   // drains vmcnt (global_load_lds)

  // ---- K loop: 8 steps of 32; unroll 1 keeps B-loads per-iter (VGPR control) ----
#pragma unroll 1
  for (int ks = 0; ks < 8; ++ks) {
    i32x4 a[4], b[4];
#pragma unroll
    for (int fm = 0; fm < 4; ++fm) {
      int r = fm * 16 + llo;
      int cb = (ks * 64 + lhi * 16) ^ ((r & 7) << 4);
      a[fm] = *reinterpret_cast<const i32x4*>((const char*)As + r * 512 + cb);
    }
    int koff = (MODE == 0) ? ((ks & 3) * 32 + lhi * 8 + ((ks >= 4) ? 32768 : 0))
                           : (ks * 32 + lhi * 8);
#pragma unroll
    for (int fn = 0; fn < 4; ++fn)
      b[fn] = *reinterpret_cast<const i32x4*>(bp[fn] + koff);
#pragma unroll
    for (int fm = 0; fm < 4; ++fm)
#pragma unroll
      for (int fn = 0; fn < 4; ++fn)
        asm("v_mfma_f32_16x16x32_bf16 %0, %1, %2, %0"
            : "+v"(acc[fm][fn]) : "v"(a[fm]), "v"(b[fn]));
  }

  asm volatile("s_nop 7\n\ts_nop 7");   // MFMA -> VALU read hazard guard

  // ---- epilogue: C/D layout col=lane&15, row=(lane>>4)*4+reg ----
#pragma unroll
  for (int fm = 0; fm < 4; ++fm) {
#pragma unroll
    for (int fn = 0; fn < 4; ++fn) {
      int col = wave * 64 + fn * 16 + llo;
#pragma unroll
      for (int j = 0; j < 4; ++j) {
        int row = row0 + fm * 16 + lhi * 4 + j;
        if (row < NN) {
          float v = acc[fm][fn][j] + bv[fn];
          if (MODE == 0) {
            v = fmaxf(v, 0.f);
            outb[(size_t)row * 256 + col] = f2bf(v);
          } else if (wave < 2) {
            outb[(size_t)row * 128 + col] = f2bf(v);
          } else {
            outf[(size_t)row * 128 + (col - 128)] = v;
          }
        }
      }
    }
  }
}

extern "C" void kernel_launch(void* const* d_in, const int* in_sizes, int n_in,
                              void* d_out, int out_size, void* d_ws, size_t ws_size,
                              hipStream_t stream) {
  const float* x   = (const float*)d_in[0];
  const int*   ei  = (const int*)d_in[1];
  const float* W1l = (const float*)d_in[2];
  const float* b1  = (const float*)d_in[3];
  const float* W1r = (const float*)d_in[4];
  const float* W2l = (const float*)d_in[5];
  const float* b2  = (const float*)d_in[6];
  const float* W2r = (const float*)d_in[7];
  float* out = (float*)d_out;

  char* ws = (char*)d_ws;
  float*          inv    = (float*)(ws);
  int*            deg    = (int*)(ws + 0x80000);
  int*            offs   = (int*)(ws + 0x100000);
  int*            bsum   = (int*)(ws + 0x200000);
  unsigned short* Wb     = (unsigned short*)(ws + 0x280000);  // 4 x 32768 bf16, packed
  int*            eidx   = (int*)(ws + 0x400000);
  unsigned short* xb     = (unsigned short*)(ws + 0x800000);   // [NN,128] bf16
  unsigned short* m1b    = (unsigned short*)(ws + 0x2200000);  // [NN,128] bf16
  unsigned short* hb     = (unsigned short*)(ws + 0x3C00000);  // [NN,256] bf16
  unsigned short* hWb    = (unsigned short*)(ws + 0x6E00000);  // [NN,128] bf16
  int*            rord   = (int*)(ws + 0x8600000);             // [NE] int

  const int* src = ei;
  const int* dst = ei + NE;
  const int NB = (NN + 1023) / 1024;  // 98

  // ---- CSR build (fill is atomic-free via degree ordinals) ----
  hipMemsetAsync(deg, 0, NN * sizeof(int), stream);
  degree_k<<<(NE + 255) / 256, 256, 0, stream>>>(dst, deg, rord);
  scan1_k<<<NB, 256, 0, stream>>>(deg, offs, bsum, inv);
  scan2_k<<<1, 256, 0, stream>>>(bsum, NB);
  scan3_k<<<NB, 256, 0, stream>>>(offs, bsum);
  fill_k<<<(NE + 255) / 256, 256, 0, stream>>>(src, dst, offs, rord, eidx);

  // ---- casts ----
  cast_x_k<<<(NN * 128 / 4 + 255) / 256, 256, 0, stream>>>(x, xb);
  cast_w4_k<<<(4 * 32768 + 255) / 256, 256, 0, stream>>>(W1l, W1r, W2l, W2r, Wb);

  const int GB = (NN + 63) / 64;  // 1563

  // ---- layer 1: m1 = gather(x); h = relu([m1|x] @ [W1l|W1r]^T + b1) ----
  gather_k<false><<<(NN + 15) / 16, 256, 0, stream>>>(xb, offs, deg, inv, eidx, m1b, nullptr);
  mgemm_k<0><<<GB, 256, 0, stream>>>(m1b, xb, Wb, b1, hb, nullptr);

  // ---- layer 2 (transform-first, fused dual-output):
  //      hW = h@W2l.T (bf16), out = h@W2r.T + b2 (f32); then out += inv*gather(hW) ----
  mgemm_k<1><<<GB, 256, 0, stream>>>(hb, nullptr, Wb + 65536, b2, hWb, out);
  gather_k<true><<<(NN + 15) / 16, 256, 0, stream>>>(hWb, offs, deg, inv, eidx, nullptr, out);
}

// Round 7
// 226.270 us; speedup vs baseline: 19.6637x; 1.1046x over previous
//
#include <hip/hip_runtime.h>

#define NN 100000
#define NE 800000

typedef __attribute__((ext_vector_type(4))) float f32x4;
typedef __attribute__((ext_vector_type(4))) int   i32x4;
typedef __attribute__((ext_vector_type(8))) unsigned short u16x8;

__device__ __forceinline__ unsigned short f2bf(float f) {
  unsigned u = __float_as_uint(f);
  return (unsigned short)((u + 0x7FFFu + ((u >> 16) & 1u)) >> 16);
}
__device__ __forceinline__ float bf2f(unsigned short b) {
  return __uint_as_float(((unsigned)b) << 16);
}

// ---------------- CSR build ----------------
__global__ void degree_k(const int* __restrict__ dst, int* __restrict__ deg,
                         int* __restrict__ rord) {
  int e = blockIdx.x * 256 + threadIdx.x;
  if (e < NE) rord[e] = atomicAdd(&deg[dst[e]], 1);
}

__global__ __launch_bounds__(256) void scan1_k(const int* __restrict__ deg,
    int* __restrict__ offs, int* __restrict__ bsum, float* __restrict__ inv) {
  __shared__ int s[256];
  int t = threadIdx.x;
  int base = blockIdx.x * 1024 + t * 4;
  int v[4], tsum = 0;
#pragma unroll
  for (int k = 0; k < 4; ++k) {
    int i = base + k;
    v[k] = (i < NN) ? deg[i] : 0;
    tsum += v[k];
    if (i < NN) inv[i] = 1.0f / fmaxf((float)v[k], 1.0f);
  }
  s[t] = tsum; __syncthreads();
  int val = tsum;
#pragma unroll
  for (int off = 1; off < 256; off <<= 1) {
    int x = (t >= off) ? s[t - off] : 0;
    __syncthreads();
    val += x; s[t] = val;
    __syncthreads();
  }
  int excl = val - tsum;
  if (t == 255) bsum[blockIdx.x] = val;
  int run = excl;
#pragma unroll
  for (int k = 0; k < 4; ++k) { int i = base + k; if (i < NN) offs[i] = run; run += v[k]; }
}

__global__ __launch_bounds__(256) void scan2_k(int* __restrict__ bsum, int nb) {
  __shared__ int s[256];
  int t = threadIdx.x;
  int v = (t < nb) ? bsum[t] : 0;
  s[t] = v; __syncthreads();
  int val = v;
#pragma unroll
  for (int off = 1; off < 256; off <<= 1) {
    int x = (t >= off) ? s[t - off] : 0;
    __syncthreads();
    val += x; s[t] = val;
    __syncthreads();
  }
  if (t < nb) bsum[t] = val - v;
}

__global__ __launch_bounds__(256) void scan3_k(int* __restrict__ offs,
    const int* __restrict__ bsum) {
  int base = blockIdx.x * 1024 + threadIdx.x * 4;
  int add = bsum[blockIdx.x];
#pragma unroll
  for (int k = 0; k < 4; ++k) {
    int i = base + k;
    if (i < NN) offs[i] += add;
  }
}

__global__ void fill_k(const int* __restrict__ src, const int* __restrict__ dst,
    const int* __restrict__ offs, const int* __restrict__ rord,
    int* __restrict__ eidx) {
  int e = blockIdx.x * 256 + threadIdx.x;
  if (e < NE) {
    int p = offs[dst[e]] + rord[e];
    __builtin_nontemporal_store(src[e], &eidx[p]);
  }
}

// ---------------- casts ----------------
__global__ __launch_bounds__(256) void cast_x_k(const float* __restrict__ in,
    unsigned short* __restrict__ outb) {
  int i = blockIdx.x * 256 + threadIdx.x;
  if (i >= NN * 128 / 4) return;
  float4 v = *reinterpret_cast<const float4*>(in + (size_t)i * 4);
  ushort4 o;
  o.x = f2bf(v.x); o.y = f2bf(v.y); o.z = f2bf(v.z); o.w = f2bf(v.w);
  *reinterpret_cast<ushort4*>(outb + (size_t)i * 4) = o;
}

__global__ __launch_bounds__(256) void cast_w4_k(const float* __restrict__ Wa,
    const float* __restrict__ Wb, const float* __restrict__ Wc,
    const float* __restrict__ Wd, unsigned short* __restrict__ outb) {
  int i = blockIdx.x * 256 + threadIdx.x;
  if (i >= 4 * 32768) return;
  int seg = i >> 15, off = i & 32767;
  const float* s = (seg < 2) ? (seg == 0 ? Wa : Wb) : (seg == 2 ? Wc : Wd);
  outb[i] = f2bf(s[off]);
}

// ---------------- gather ----------------
// GMODE 0: outb(bf16)[node] = bf16(inv*sum(feat[nbr]))
// GMODE 2: outf(f32)[node]  = bf2f(selfb[node]) + inv*sum(feat[nbr])
template<int GMODE>
__global__ __launch_bounds__(256) void gather_k(const unsigned short* __restrict__ feat,
    const int* __restrict__ offs, const int* __restrict__ deg,
    const float* __restrict__ inv, const int* __restrict__ eidx,
    const unsigned short* __restrict__ selfb,
    unsigned short* __restrict__ outb, float* __restrict__ outf) {
  int node = blockIdx.x * 16 + (threadIdx.x >> 4);
  int l = threadIdx.x & 15;
  if (node >= NN) return;
  int st = offs[node], n = deg[node];
  float a[8];
#pragma unroll
  for (int k = 0; k < 8; ++k) a[k] = 0.f;

  int j = 0;
  for (; j + 4 <= n; j += 4) {
    int s0 = eidx[st + j + 0];
    int s1 = eidx[st + j + 1];
    int s2 = eidx[st + j + 2];
    int s3 = eidx[st + j + 3];
    u16x8 r0 = *reinterpret_cast<const u16x8*>(feat + (size_t)s0 * 128 + l * 8);
    u16x8 r1 = *reinterpret_cast<const u16x8*>(feat + (size_t)s1 * 128 + l * 8);
    u16x8 r2 = *reinterpret_cast<const u16x8*>(feat + (size_t)s2 * 128 + l * 8);
    u16x8 r3 = *reinterpret_cast<const u16x8*>(feat + (size_t)s3 * 128 + l * 8);
#pragma unroll
    for (int k = 0; k < 8; ++k)
      a[k] += (bf2f(r0[k]) + bf2f(r1[k])) + (bf2f(r2[k]) + bf2f(r3[k]));
  }
  for (; j < n; ++j) {
    int s = eidx[st + j];
    u16x8 r = *reinterpret_cast<const u16x8*>(feat + (size_t)s * 128 + l * 8);
#pragma unroll
    for (int k = 0; k < 8; ++k) a[k] += bf2f(r[k]);
  }

  float sc = inv[node];
  if (GMODE == 2) {
    u16x8 sb = *reinterpret_cast<const u16x8*>(selfb + (size_t)node * 128 + l * 8);
    float4 o0, o1;
    o0.x = bf2f(sb[0]) + sc * a[0]; o0.y = bf2f(sb[1]) + sc * a[1];
    o0.z = bf2f(sb[2]) + sc * a[2]; o0.w = bf2f(sb[3]) + sc * a[3];
    o1.x = bf2f(sb[4]) + sc * a[4]; o1.y = bf2f(sb[5]) + sc * a[5];
    o1.z = bf2f(sb[6]) + sc * a[6]; o1.w = bf2f(sb[7]) + sc * a[7];
    float* po = outf + (size_t)node * 128 + l * 8;
    *reinterpret_cast<float4*>(po) = o0;
    *reinterpret_cast<float4*>(po + 4) = o1;
  } else {
    u16x8 o;
#pragma unroll
    for (int k = 0; k < 8; ++k) o[k] = f2bf(sc * a[k]);
    *reinterpret_cast<u16x8*>(outb + (size_t)node * 128 + l * 8) = o;
  }
}

// ---------------- persistent bf16 MFMA GEMM (64 rows x 256 cols / panel) --------
// Grid = 512 persistent blocks (2/CU, 64KB LDS dbuf, VGPR<=256 via launch_bounds).
// B fragments (whole weight slice for this wave's 64 cols) preloaded ONCE to regs.
// Panel loop: stage(next)->vmcnt(8)->raw barrier->MFMA+stores->raw barrier.
// Counted vmcnt (never 0) keeps next panel's loads in flight across barriers.
// MODE 0 (layer 1): A=[A1|A2] k-concat; B k-concat (W1l|+32768 W1r, each [256,128]);
//   out = bf16 relu(C+bias) -> outb [NN,256].
// MODE 1 (layer 2): A=A1 [M,256]; B out-concat (W2l|+32768 W2r, each [128,256]);
//   waves 0-1 -> outb = bf16(h@W2l) [NN,128]; waves 2-3 -> outb2 = bf16(h@W2r + bias).
template<int MODE>
__global__ __launch_bounds__(256, 2) void mgemm_k(
    const unsigned short* __restrict__ A1, const unsigned short* __restrict__ A2,
    const unsigned short* __restrict__ Wbase, const float* __restrict__ bias,
    unsigned short* __restrict__ outb, unsigned short* __restrict__ outb2) {
  __shared__ unsigned short As[2][64 * 256];   // 2 x 32 KB, row stride 512 B
  const int t = threadIdx.x;
  const int wave = t >> 6, lane = t & 63;
  const int lhi = lane >> 4, llo = lane & 15;

  // ---- B fragments + bias, loaded once (weights are L2-resident) ----
  i32x4 bfrag[8][4];
  float bv[4];
#pragma unroll
  for (int fn = 0; fn < 4; ++fn) {
    int c = wave * 64 + fn * 16 + llo;
    const unsigned short* rowp;
    if (MODE == 0) {
      rowp = Wbase + (size_t)c * 128;
      bv[fn] = bias[c];
    } else {
      rowp = Wbase + (wave >= 2 ? 32768 : 0) + (size_t)(c & 127) * 256;
      bv[fn] = (wave >= 2) ? bias[c & 127] : 0.f;
    }
#pragma unroll
    for (int ks = 0; ks < 8; ++ks) {
      int koff = (MODE == 0) ? ((ks & 3) * 32 + lhi * 8 + ((ks >= 4) ? 32768 : 0))
                             : (ks * 32 + lhi * 8);
      bfrag[ks][fn] = *reinterpret_cast<const i32x4*>(rowp + koff);
    }
  }

  // ---- staging helper: panel rows [row0,row0+64) -> buf; swizzled src, linear LDS ----
  auto stage = [&](int buf, int row0) {
#pragma unroll
    for (int c = 0; c < 8; ++c) {
      int chunk = wave * 8 + c;
      int tb = chunk * 1024 + lane * 16;
      int r = tb >> 9;
      int cb = tb & 511;
      int cbs = cb ^ ((r & 7) << 4);     // involutive XOR swizzle (bits 4-6)
      int gr = min(row0 + r, NN - 1);
      const char* gsrc;
      if (MODE == 0) {
        const unsigned short* Asel = (cbs < 256) ? A1 : A2;
        gsrc = (const char*)(Asel + (size_t)gr * 128) + (cbs & 255);
      } else {
        gsrc = (const char*)(A1 + (size_t)gr * 256) + cbs;
      }
      __builtin_amdgcn_global_load_lds(
          (const __attribute__((address_space(1))) void*)gsrc,
          (__attribute__((address_space(3))) void*)((char*)As + buf * 32768 + chunk * 1024),
          16, 0, 0);
    }
  };

  const int npan = (NN + 63) >> 6;   // 1563
  int p = blockIdx.x;
  stage(0, p * 64);
  int cur = 0;

#pragma unroll 1
  for (; p < npan; p += gridDim.x) {
    int pn = p + gridDim.x;
    if (pn < npan) stage(cur ^ 1, pn * 64);
    // counted wait: in-order retirement => <=8 outstanding means current buffer's
    // 8 loads (issued before the 8 just staged) have landed. Never drains to 0.
    asm volatile("s_waitcnt vmcnt(8)" ::: "memory");
    __builtin_amdgcn_s_barrier();

    const int row0 = p * 64;
    f32x4 acc[4][4];
#pragma unroll
    for (int fm = 0; fm < 4; ++fm)
#pragma unroll
      for (int fn = 0; fn < 4; ++fn) acc[fm][fn] = (f32x4)0.f;

#pragma unroll
    for (int ks = 0; ks < 8; ++ks) {
      i32x4 a[4];
#pragma unroll
      for (int fm = 0; fm < 4; ++fm) {
        int r = fm * 16 + llo;
        int cb = (ks * 64 + lhi * 16) ^ ((r & 7) << 4);
        a[fm] = *reinterpret_cast<const i32x4*>((const char*)As + cur * 32768 + r * 512 + cb);
      }
#pragma unroll
      for (int fm = 0; fm < 4; ++fm)
#pragma unroll
        for (int fn = 0; fn < 4; ++fn)
          asm("v_mfma_f32_16x16x32_bf16 %0, %1, %2, %0"
              : "+v"(acc[fm][fn]) : "v"(a[fm]), "v"(bfrag[ks][fn]));
    }

    asm volatile("s_nop 7\n\ts_nop 7");   // MFMA -> VALU read hazard guard

#pragma unroll
    for (int fm = 0; fm < 4; ++fm) {
#pragma unroll
      for (int fn = 0; fn < 4; ++fn) {
        int col = wave * 64 + fn * 16 + llo;
#pragma unroll
        for (int j = 0; j < 4; ++j) {
          int row = row0 + fm * 16 + lhi * 4 + j;
          if (row < NN) {
            float v = acc[fm][fn][j] + bv[fn];
            if (MODE == 0) {
              v = fmaxf(v, 0.f);
              outb[(size_t)row * 256 + col] = f2bf(v);
            } else if (wave < 2) {
              outb[(size_t)row * 128 + col] = f2bf(v);
            } else {
              outb2[(size_t)row * 128 + (col - 128)] = f2bf(v);
            }
          }
        }
      }
    }
    __builtin_amdgcn_s_barrier();  // all waves done reading As[cur] before restage
    cur ^= 1;
  }
}

extern "C" void kernel_launch(void* const* d_in, const int* in_sizes, int n_in,
                              void* d_out, int out_size, void* d_ws, size_t ws_size,
                              hipStream_t stream) {
  const float* x   = (const float*)d_in[0];
  const int*   ei  = (const int*)d_in[1];
  const float* W1l = (const float*)d_in[2];
  const float* b1  = (const float*)d_in[3];
  const float* W1r = (const float*)d_in[4];
  const float* W2l = (const float*)d_in[5];
  const float* b2  = (const float*)d_in[6];
  const float* W2r = (const float*)d_in[7];
  float* out = (float*)d_out;

  char* ws = (char*)d_ws;
  float*          inv    = (float*)(ws);
  int*            deg    = (int*)(ws + 0x80000);
  int*            offs   = (int*)(ws + 0x100000);
  int*            bsum   = (int*)(ws + 0x200000);
  unsigned short* Wb     = (unsigned short*)(ws + 0x280000);  // 4 x 32768 bf16, packed
  int*            eidx   = (int*)(ws + 0x400000);
  unsigned short* xb     = (unsigned short*)(ws + 0x800000);   // [NN,128] bf16
  unsigned short* m1b    = (unsigned short*)(ws + 0x2200000);  // [NN,128] bf16 (layer1); selfb (layer2)
  unsigned short* hb     = (unsigned short*)(ws + 0x3C00000);  // [NN,256] bf16
  unsigned short* hWb    = (unsigned short*)(ws + 0x6E00000);  // [NN,128] bf16
  int*            rord   = (int*)(ws + 0x8600000);             // [NE] int
  unsigned short* selfb  = m1b;   // m1b dead after layer-1 GEMM

  const int* src = ei;
  const int* dst = ei + NE;
  const int NB = (NN + 1023) / 1024;  // 98

  // ---- CSR build (fill is atomic-free via degree ordinals) ----
  hipMemsetAsync(deg, 0, NN * sizeof(int), stream);
  degree_k<<<(NE + 255) / 256, 256, 0, stream>>>(dst, deg, rord);
  scan1_k<<<NB, 256, 0, stream>>>(deg, offs, bsum, inv);
  scan2_k<<<1, 256, 0, stream>>>(bsum, NB);
  scan3_k<<<NB, 256, 0, stream>>>(offs, bsum);
  fill_k<<<(NE + 255) / 256, 256, 0, stream>>>(src, dst, offs, rord, eidx);

  // ---- casts ----
  cast_x_k<<<(NN * 128 / 4 + 255) / 256, 256, 0, stream>>>(x, xb);
  cast_w4_k<<<(4 * 32768 + 255) / 256, 256, 0, stream>>>(W1l, W1r, W2l, W2r, Wb);

  // ---- layer 1: m1 = gather(x); h = relu([m1|x] @ [W1l|W1r]^T + b1) ----
  gather_k<0><<<(NN + 15) / 16, 256, 0, stream>>>(xb, offs, deg, inv, eidx, nullptr, m1b, nullptr);
  mgemm_k<0><<<512, 256, 0, stream>>>(m1b, xb, Wb, b1, hb, nullptr);

  // ---- layer 2 (transform-first): hWb = bf16(h@W2l), selfb = bf16(h@W2r + b2);
  //      out = selfb + inv * gather(hWb)  (single f32 write, no RMW) ----
  mgemm_k<1><<<512, 256, 0, stream>>>(hb, nullptr, Wb + 65536, b2, hWb, selfb);
  gather_k<2><<<(NN + 15) / 16, 256, 0, stream>>>(hWb, offs, deg, inv, eidx, selfb, nullptr, out);
}